// Round 7
// baseline (257.588 us; speedup 1.0000x reference)
//
#include <hip/hip_runtime.h>
#include <math.h>

#define S_   4096
#define H_   8
#define D_   64
#define HD_  512
#define NCH  256   // chunks per batch
#define LCH  16    // seq steps per chunk
#define RC   128   // rows per chunk = LCH*H_  (h-major: row = h*16 + s)
#define NCOL 2048  // scan columns = B * H * D

typedef __bf16 bf16x8 __attribute__((ext_vector_type(8)));
typedef float  f32x4  __attribute__((ext_vector_type(4)));

__device__ __forceinline__ float sigm(float v) { return 1.f / (1.f + __expf(-v)); }

// XOR-swizzled byte offset into the 128x128 bf16 A-tile (row stride 256B).
__device__ __forceinline__ int swzA(int row, int bytecol) {
  return row * 256 + (bytecol ^ ((row & 7) << 4));
}

// ---------------- K0: transpose weights to bf16 [n][k] ----------------
__global__ __launch_bounds__(256) void k_wt(const float* __restrict__ Wh,
                                            const float* __restrict__ Wo,
                                            __bf16* __restrict__ Wth,
                                            __bf16* __restrict__ Wto) {
  int idx = blockIdx.x * 256 + threadIdx.x;   // 0..32767
  if (idx < 24576) {
    int k = idx / 192, n = idx % 192;
    Wth[n * 128 + k] = (__bf16)Wh[idx];
  } else {
    int j = idx - 24576;                       // 0..8191, W_og[k][n], n<64
    int k = j >> 6, n = j & 63;
    Wto[n * 128 + k] = (__bf16)Wo[j];
  }
}

// ---------------- K1: per-chunk sums of x ----------------
__global__ __launch_bounds__(512) void k_chunk_sums(const float* __restrict__ x,
                                                    float* __restrict__ sums) {
  const int b = blockIdx.x >> 8, c = blockIdx.x & 255;
  const int t = threadIdx.x;
  const float* p = x + ((size_t)b * S_ + c * LCH) * HD_ + t;
  float acc = 0.f;
  #pragma unroll
  for (int i = 0; i < LCH; ++i) acc += p[(size_t)i * HD_];
  sums[((size_t)b * NCH + c) * HD_ + t] = acc;
}

// ---------------- 3-level exclusive scan of chunk sums (x offsets) -----------
__global__ __launch_bounds__(256) void kx_l1(const float* __restrict__ sums,
                                             float* __restrict__ gx) {
  int w = blockIdx.x * 256 + threadIdx.x;    // 0..32767
  int grp = w >> 11, col = w & 2047;
  int b = col >> 9, hd = col & 511;
  float s = 0.f;
  #pragma unroll
  for (int i = 0; i < 16; ++i)
    s += sums[((size_t)(b * NCH + grp * 16 + i)) * HD_ + hd];
  gx[grp * NCOL + col] = s;
}
__global__ __launch_bounds__(256) void kx_l2(float* __restrict__ gx) {
  int col = blockIdx.x * 256 + threadIdx.x;  // 0..2047
  float run = 0.f;
  #pragma unroll
  for (int g = 0; g < 16; ++g) {
    float v = gx[g * NCOL + col];
    gx[g * NCOL + col] = run;
    run += v;
  }
}
__global__ __launch_bounds__(256) void kx_l3(float* __restrict__ sums,
                                             const float* __restrict__ gx) {
  int w = blockIdx.x * 256 + threadIdx.x;
  int grp = w >> 11, col = w & 2047;
  int b = col >> 9, hd = col & 511;
  float run = gx[grp * NCOL + col];
  #pragma unroll
  for (int i = 0; i < 16; ++i) {
    size_t idx = ((size_t)(b * NCH + grp * 16 + i)) * HD_ + hd;
    float v = sums[idx];
    sums[idx] = run;
    run += v;
  }
}

// ---------------- shared device body (512 thr, 8 waves, wave = head) ---------
// LN column-parallel: thread owns one column, run[17] in registers, ONE
// two-level reduction (2 barriers). After stats everything is wave-local.
// WRITE_TOT=true : write per-chunk scan totals cA/cB.
// WRITE_TOT=false: fused cell-emit (needs cin) -> bf16 cell into A-tile.
template <bool WRITE_TOT>
__device__ __forceinline__ void ln_gates512(const float* __restrict__ x,
                                            const float* __restrict__ offs,
                                            const float* __restrict__ gamma,
                                            const float* __restrict__ beta,
                                            const __bf16* __restrict__ Wth,
                                            const float* __restrict__ bh,
                                            char* Al,
                                            float2 (*redW)[LCH],
                                            float2* redF,
                                            int b, int c, int cid,
                                            const float* __restrict__ cin,
                                            float* __restrict__ cA,
                                            float* __restrict__ cB) {
  const int t = threadIdx.x;
  const int wave = t >> 6, lane = t & 63;
  const int quad = lane >> 4, l16 = lane & 15;

  // ---- LN phase ----
  {
    const int hh = wave, dd = t & 63;      // column hd = t, head = wave
    const float* xp = x + ((size_t)b * S_ + c * LCH) * HD_ + t;
    float run[LCH + 1];
    run[0] = offs[((size_t)(b * NCH + c)) * HD_ + t];
    #pragma unroll
    for (int s = 0; s < LCH; ++s) run[s + 1] = run[s] + xp[(size_t)s * HD_];

    // wave-level reduce of all 16 step-values (independent, pipelined)
    #pragma unroll
    for (int s = 0; s < LCH; ++s) {
      float v = run[s], v2 = run[s] * run[s];
      #pragma unroll
      for (int o = 32; o; o >>= 1) { v += __shfl_xor(v, o); v2 += __shfl_xor(v2, o); }
      if (lane == 0) redW[wave][s] = make_float2(v, v2);
    }
    __syncthreads();
    if (t < LCH) {
      float s1 = 0.f, s2 = 0.f;
      #pragma unroll
      for (int w = 0; w < 8; ++w) { float2 p = redW[w][t]; s1 += p.x; s2 += p.y; }
      float m = s1 * (1.f / HD_);
      float var = fmaf(-m, m, s2 * (1.f / HD_));
      redF[t] = make_float2(m, rsqrtf(var + 1e-5f));
    }
    __syncthreads();

    const float g = gamma[t], be = beta[t];
    #pragma unroll
    for (int s = 0; s < LCH; ++s) {
      float2 st = redF[s];
      float lnv = (run[s] - st.x) * st.y * g + be;
      float xs = run[s + 1] - run[s];      // == x (exact recovery)
      int row = hh * 16 + s;
      *(__bf16*)(Al + swzA(row, dd * 2)) = (__bf16)xs;
      *(__bf16*)(Al + swzA(row, 128 + dd * 2)) = (__bf16)lnv;
    }
  }
  // No barrier: A-tile rows [wave*16, wave*16+16) are written and read only
  // by this wave; per-wave LDS ops complete in order.

  // ---- gates GEMM (3 register-lean N-passes) + chunk-local scan ----
  const int mt = wave;                     // head
  const int arow = mt * 16 + l16;
  float fv[16], iv[16];
  // pass F (N cols 64..127)
  {
    f32x4 acc[4];
    #pragma unroll
    for (int nt = 0; nt < 4; ++nt) acc[nt] = (f32x4){0.f, 0.f, 0.f, 0.f};
    #pragma unroll
    for (int ks = 0; ks < 4; ++ks) {
      bf16x8 af = *(const bf16x8*)(Al + swzA(arow, ks * 64 + quad * 16));
      #pragma unroll
      for (int nt = 0; nt < 4; ++nt) {
        bf16x8 bf_ = *(const bf16x8*)(Wth + ((4 + nt) * 16 + l16) * 128 + ks * 32 + quad * 8);
        acc[nt] = __builtin_amdgcn_mfma_f32_16x16x32_bf16(af, bf_, acc[nt], 0, 0, 0);
      }
    }
    #pragma unroll
    for (int nt = 0; nt < 4; ++nt) {
      float bb_ = bh[64 + nt * 16 + l16];
      #pragma unroll
      for (int r = 0; r < 4; ++r) fv[nt * 4 + r] = sigm(acc[nt][r] + bb_);
    }
  }
  // pass I (N cols 0..63)
  {
    f32x4 acc[4];
    #pragma unroll
    for (int nt = 0; nt < 4; ++nt) acc[nt] = (f32x4){0.f, 0.f, 0.f, 0.f};
    #pragma unroll
    for (int ks = 0; ks < 4; ++ks) {
      bf16x8 af = *(const bf16x8*)(Al + swzA(arow, ks * 64 + quad * 16));
      #pragma unroll
      for (int nt = 0; nt < 4; ++nt) {
        bf16x8 bf_ = *(const bf16x8*)(Wth + (nt * 16 + l16) * 128 + ks * 32 + quad * 8);
        acc[nt] = __builtin_amdgcn_mfma_f32_16x16x32_bf16(af, bf_, acc[nt], 0, 0, 0);
      }
    }
    #pragma unroll
    for (int nt = 0; nt < 4; ++nt) {
      float bb_ = bh[nt * 16 + l16];
      #pragma unroll
      for (int r = 0; r < 4; ++r) iv[nt * 4 + r] = sigm(acc[nt][r] + bb_);
    }
  }
  // pass H (N cols 128..191): iv becomes g = sigm(i)*relu(h)
  {
    f32x4 acc[4];
    #pragma unroll
    for (int nt = 0; nt < 4; ++nt) acc[nt] = (f32x4){0.f, 0.f, 0.f, 0.f};
    #pragma unroll
    for (int ks = 0; ks < 4; ++ks) {
      bf16x8 af = *(const bf16x8*)(Al + swzA(arow, ks * 64 + quad * 16));
      #pragma unroll
      for (int nt = 0; nt < 4; ++nt) {
        bf16x8 bf_ = *(const bf16x8*)(Wth + ((8 + nt) * 16 + l16) * 128 + ks * 32 + quad * 8);
        acc[nt] = __builtin_amdgcn_mfma_f32_16x16x32_bf16(af, bf_, acc[nt], 0, 0, 0);
      }
    }
    #pragma unroll
    for (int nt = 0; nt < 4; ++nt) {
      float bb_ = bh[128 + nt * 16 + l16];
      #pragma unroll
      for (int r = 0; r < 4; ++r)
        iv[nt * 4 + r] = iv[nt * 4 + r] * fmaxf(acc[nt][r] + bb_, 0.f);
    }
  }
  // segmented affine scan over s (4 regs x 4 quads)
  #pragma unroll
  for (int nt = 0; nt < 4; ++nt) {
    float a = 1.f, bb2 = 0.f, pa[4], pb[4];
    #pragma unroll
    for (int r = 0; r < 4; ++r) {
      float fvv = fv[nt * 4 + r], gvv = iv[nt * 4 + r];
      a = fvv * a;
      bb2 = fmaf(fvv, bb2, gvv);
      pa[r] = a; pb[r] = bb2;
    }
    if constexpr (WRITE_TOT) {
      float TA = 1.f, TB = 0.f;
      #pragma unroll
      for (int q = 0; q < 4; ++q) {
        float Aq = __shfl(a, q * 16 + l16, 64);
        float Bq = __shfl(bb2, q * 16 + l16, 64);
        TB = fmaf(Aq, TB, Bq);
        TA = Aq * TA;
      }
      if (quad == 0) {
        cA[(size_t)cid * HD_ + mt * 64 + nt * 16 + l16] = TA;
        cB[(size_t)cid * HD_ + mt * 64 + nt * 16 + l16] = TB;
      }
    } else {
      float exA = 1.f, exB = 0.f;
      #pragma unroll
      for (int q = 0; q < 3; ++q) {
        float Aq = __shfl(a, q * 16 + l16, 64);
        float Bq = __shfl(bb2, q * 16 + l16, 64);
        if (q < quad) { exB = fmaf(Aq, exB, Bq); exA = Aq * exA; }
      }
      // fused cell-emit: cell = pa*(exA*ci + exB) + pb -> bf16 LDS only
      const int dcol = nt * 16 + l16;
      float ci = cin[(size_t)cid * HD_ + mt * 64 + dcol];
      float u = fmaf(exA, ci, exB);
      #pragma unroll
      for (int r = 0; r < 4; ++r) {
        float cv = fmaf(pa[r], u, pb[r]);
        int rowl = mt * 16 + quad * 4 + r;
        *(__bf16*)(Al + swzA(rowl, 128 + dcol * 2)) = (__bf16)cv;
      }
    }
  }
}

// ---------------- K4: LN + gates GEMM + chunk scan -> cA/cB ------------------
__global__ __launch_bounds__(512) void k_gates_f(const float* __restrict__ x,
                                                 const float* __restrict__ offs,
                                                 const float* __restrict__ gamma,
                                                 const float* __restrict__ beta,
                                                 const __bf16* __restrict__ Wth,
                                                 const float* __restrict__ bh,
                                                 float* __restrict__ cA,
                                                 float* __restrict__ cB) {
  __shared__ char Al[RC * 256];
  __shared__ float2 redW[8][LCH];
  __shared__ float2 redF[LCH];
  const int cid = blockIdx.x, b = cid >> 8, c = cid & 255;
  ln_gates512<true>(x, offs, gamma, beta, Wth, bh, Al, redW, redF,
                    b, c, cid, nullptr, cA, cB);
}

// ---------------- 3-level cross-chunk cell scan ------------------------------
__global__ __launch_bounds__(256) void kc_l1(const float* __restrict__ cA,
                                             const float* __restrict__ cB,
                                             float* __restrict__ gA,
                                             float* __restrict__ gB) {
  int w = blockIdx.x * 256 + threadIdx.x;
  int grp = w >> 11, col = w & 2047;
  int b = col >> 9, hd = col & 511;
  float Ag = 1.f, Bg = 0.f;
  #pragma unroll
  for (int i = 0; i < 16; ++i) {
    size_t idx = ((size_t)(b * NCH + grp * 16 + i)) * HD_ + hd;
    float Ac = cA[idx], Bc = cB[idx];
    Bg = fmaf(Ac, Bg, Bc);
    Ag = Ac * Ag;
  }
  gA[grp * NCOL + col] = Ag;
  gB[grp * NCOL + col] = Bg;
}
__global__ __launch_bounds__(256) void kc_l2(float* __restrict__ gA,
                                             const float* __restrict__ gB,
                                             const float* __restrict__ initcx) {
  int col = blockIdx.x * 256 + threadIdx.x;   // 0..2047
  int hd = col & 511;
  float run = initcx[hd];
  #pragma unroll
  for (int g = 0; g < 16; ++g) {
    float Ag = gA[g * NCOL + col], Bg = gB[g * NCOL + col];
    gA[g * NCOL + col] = run;                 // group run-in value
    run = fmaf(Ag, run, Bg);
  }
}
__global__ __launch_bounds__(256) void kc_l3(const float* __restrict__ cA,
                                             const float* __restrict__ cB,
                                             const float* __restrict__ gA,
                                             float* __restrict__ cin) {
  int w = blockIdx.x * 256 + threadIdx.x;
  int grp = w >> 11, col = w & 2047;
  int b = col >> 9, hd = col & 511;
  float run = gA[grp * NCOL + col];
  #pragma unroll
  for (int i = 0; i < 16; ++i) {
    size_t idx = ((size_t)(b * NCH + grp * 16 + i)) * HD_ + hd;
    cin[idx] = run;
    run = fmaf(cA[idx], run, cB[idx]);
  }
}

// ---------------- K6: recompute LN+gates, fused cell emit, og GEMM, out ------
__global__ __launch_bounds__(512) void k_og_f(const float* __restrict__ x,
                                              const float* __restrict__ offs,
                                              const float* __restrict__ gamma,
                                              const float* __restrict__ beta,
                                              const __bf16* __restrict__ Wth,
                                              const __bf16* __restrict__ Wto,
                                              const float* __restrict__ bh,
                                              const float* __restrict__ bo,
                                              const float* __restrict__ cin,
                                              float* __restrict__ out) {
  __shared__ char Al[RC * 256];
  __shared__ float2 redW[8][LCH];
  __shared__ float2 redF[LCH];
  const int cid = blockIdx.x, b = cid >> 8, c = cid & 255;
  const int t = threadIdx.x;
  const int wave = t >> 6, lane = t & 63;
  const int quad = lane >> 4, l16 = lane & 15;

  ln_gates512<false>(x, offs, gamma, beta, Wth, bh, Al, redW, redF,
                     b, c, cid, cin, nullptr, nullptr);
  // No barrier: og GEMM reads only this wave's head rows (wave-local).

  const int mt = wave;
  const int arow = mt * 16 + l16;
  f32x4 acc[4];
  #pragma unroll
  for (int nt = 0; nt < 4; ++nt) acc[nt] = (f32x4){0.f, 0.f, 0.f, 0.f};
  #pragma unroll
  for (int ks = 0; ks < 4; ++ks) {
    bf16x8 af = *(const bf16x8*)(Al + swzA(arow, ks * 64 + quad * 16));
    #pragma unroll
    for (int nt = 0; nt < 4; ++nt) {
      bf16x8 bf_ = *(const bf16x8*)(Wto + (nt * 16 + l16) * 128 + ks * 32 + quad * 8);
      acc[nt] = __builtin_amdgcn_mfma_f32_16x16x32_bf16(af, bf_, acc[nt], 0, 0, 0);
    }
  }
  #pragma unroll
  for (int nt = 0; nt < 4; ++nt) {
    const int dcol = nt * 16 + l16;
    float bv = bo[dcol];
    #pragma unroll
    for (int r = 0; r < 4; ++r) {
      int rowl = mt * 16 + quad * 4 + r;
      int s = quad * 4 + r;
      float og = sigm(acc[nt][r] + bv);
      float cv = (float)*(const __bf16*)(Al + swzA(rowl, 128 + dcol * 2));
      out[(((size_t)b * S_ + c * LCH + s) * H_ + mt) * D_ + dcol] = og * cv;
    }
  }
}

extern "C" void kernel_launch(void* const* d_in, const int* in_sizes, int n_in,
                              void* d_out, int out_size, void* d_ws, size_t ws_size,
                              hipStream_t stream) {
  const float* x      = (const float*)d_in[0];
  const float* W_hid  = (const float*)d_in[1];
  const float* b_hid  = (const float*)d_in[2];
  const float* W_og   = (const float*)d_in[3];
  const float* b_og   = (const float*)d_in[4];
  const float* gamma  = (const float*)d_in[5];
  const float* beta   = (const float*)d_in[6];
  const float* initcx = (const float*)d_in[7];
  float* out = (float*)d_out;
  float* ws  = (float*)d_ws;

  // ws layout (floats):
  float*  buf0 = ws;                      // sums -> offs (in place)   524288
  float*  cA   = ws + 524288;             //                           524288
  float*  cB   = cA + 524288;             //                           524288
  float*  cin  = cB + 524288;             //                           524288
  float*  gx   = cin + 524288;            // x-offset group sums        32768
  float*  gA   = gx + 32768;              // cell group compose A       32768
  float*  gB   = gA + 32768;              // cell group compose B       32768
  __bf16* Wth  = (__bf16*)(gB + 32768);   // [192][128] bf16
  __bf16* Wto  = Wth + 24576;             // [64][128] bf16

  k_wt         <<<128,  256, 0, stream>>>(W_hid, W_og, Wth, Wto);
  k_chunk_sums <<<1024, 512, 0, stream>>>(x, buf0);
  kx_l1        <<<128,  256, 0, stream>>>(buf0, gx);
  kx_l2        <<<8,    256, 0, stream>>>(gx);
  kx_l3        <<<128,  256, 0, stream>>>(buf0, gx);
  k_gates_f    <<<1024, 512, 0, stream>>>(x, buf0, gamma, beta, Wth, b_hid, cA, cB);
  kc_l1        <<<128,  256, 0, stream>>>(cA, cB, gA, gB);
  kc_l2        <<<8,    256, 0, stream>>>(gA, gB, initcx);
  kc_l3        <<<128,  256, 0, stream>>>(cA, cB, gA, cin);
  k_og_f       <<<1024, 512, 0, stream>>>(x, buf0, gamma, beta, Wth, Wto,
                                          b_hid, b_og, cin, out);
}

// Round 8
// 214.048 us; speedup vs baseline: 1.2034x; 1.2034x over previous
//
#include <hip/hip_runtime.h>
#include <math.h>

#define S_   4096
#define H_   8
#define D_   64
#define HD_  512
#define NCH  256   // chunks per batch
#define LCH  16    // seq steps per chunk
#define NCOL 2048  // scan columns = B * H * D

typedef __bf16 bf16x8 __attribute__((ext_vector_type(8)));
typedef float  f32x4  __attribute__((ext_vector_type(4)));

__device__ __forceinline__ float sigm(float v) { return 1.f / (1.f + __expf(-v)); }

// XOR-swizzled byte offset into a [rows][128] bf16 LDS tile (row stride 256B).
__device__ __forceinline__ int swzA(int row, int bytecol) {
  return row * 256 + (bytecol ^ ((row & 7) << 4));
}

// ---------------- K0: transpose weights to bf16 [n][k] ----------------
__global__ __launch_bounds__(256) void k_wt(const float* __restrict__ Wh,
                                            const float* __restrict__ Wo,
                                            __bf16* __restrict__ Wth,
                                            __bf16* __restrict__ Wto) {
  int idx = blockIdx.x * 256 + threadIdx.x;   // 0..32767
  if (idx < 24576) {
    int k = idx / 192, n = idx % 192;
    Wth[n * 128 + k] = (__bf16)Wh[idx];
  } else {
    int j = idx - 24576;                       // 0..8191, W_og[k][n], n<64
    int k = j >> 6, n = j & 63;
    Wto[n * 128 + k] = (__bf16)Wo[j];
  }
}

// ---------------- K1: per-chunk sums of x ----------------
__global__ __launch_bounds__(512) void k_chunk_sums(const float* __restrict__ x,
                                                    float* __restrict__ sums) {
  const int b = blockIdx.x >> 8, c = blockIdx.x & 255;
  const int t = threadIdx.x;
  const float* p = x + ((size_t)b * S_ + c * LCH) * HD_ + t;
  float acc = 0.f;
  #pragma unroll
  for (int i = 0; i < LCH; ++i) acc += p[(size_t)i * HD_];
  sums[((size_t)b * NCH + c) * HD_ + t] = acc;
}

// ---------------- 3-level exclusive scan of chunk sums (x offsets) -----------
__global__ __launch_bounds__(256) void kx_l1(const float* __restrict__ sums,
                                             float* __restrict__ gx) {
  int w = blockIdx.x * 256 + threadIdx.x;    // 0..32767
  int grp = w >> 11, col = w & 2047;
  int b = col >> 9, hd = col & 511;
  float s = 0.f;
  #pragma unroll
  for (int i = 0; i < 16; ++i)
    s += sums[((size_t)(b * NCH + grp * 16 + i)) * HD_ + hd];
  gx[grp * NCOL + col] = s;
}
__global__ __launch_bounds__(256) void kx_l2(float* __restrict__ gx) {
  int col = blockIdx.x * 256 + threadIdx.x;  // 0..2047
  float run = 0.f;
  #pragma unroll
  for (int g = 0; g < 16; ++g) {
    float v = gx[g * NCOL + col];
    gx[g * NCOL + col] = run;
    run += v;
  }
}
__global__ __launch_bounds__(256) void kx_l3(float* __restrict__ sums,
                                             const float* __restrict__ gx) {
  int w = blockIdx.x * 256 + threadIdx.x;
  int grp = w >> 11, col = w & 2047;
  int b = col >> 9, hd = col & 511;
  float run = gx[grp * NCOL + col];
  #pragma unroll
  for (int i = 0; i < 16; ++i) {
    size_t idx = ((size_t)(b * NCH + grp * 16 + i)) * HD_ + hd;
    float v = sums[idx];
    sums[idx] = run;
    run += v;
  }
}

// -------- per-chunk body: LN -> LDS A-tile, 12-acc gates GEMM, chunk scan ----
// Runs on one 512-thread half (8 waves, wave = head). Weights read from LDS.
// WRITE_TOT=true : write per-chunk scan totals cA/cB.
// WRITE_TOT=false: fused cell-emit (needs cin) -> bf16 cell into A-tile.
template <bool WRITE_TOT>
__device__ __forceinline__ void chunk_body(const float* __restrict__ x,
                                           const float* __restrict__ offs,
                                           const float* __restrict__ gamma,
                                           const float* __restrict__ beta,
                                           const float* __restrict__ bh,
                                           char* Alh, const char* WthL,
                                           float2 (*redW)[LCH],   // [8][16]
                                           float2* redF,          // [16]
                                           int cid,
                                           const float* __restrict__ cin,
                                           float* __restrict__ cA,
                                           float* __restrict__ cB) {
  const int t = threadIdx.x;
  const int th = t & 511;                 // column within chunk
  const int wave = (t >> 6) & 7;          // head
  const int lane = t & 63, quad = lane >> 4, l16 = lane & 15;
  const int b = cid >> 8, c = cid & 255;

  // ---- LN: column-parallel, one two-level reduction ----
  {
    const int dd = th & 63;
    const float* xp = x + ((size_t)b * S_ + c * LCH) * HD_ + th;
    float run[LCH + 1];
    run[0] = offs[(size_t)cid * HD_ + th];
    #pragma unroll
    for (int s = 0; s < LCH; ++s) run[s + 1] = run[s] + xp[(size_t)s * HD_];
    #pragma unroll
    for (int s = 0; s < LCH; ++s) {
      float v = run[s], v2 = run[s] * run[s];
      #pragma unroll
      for (int o = 32; o; o >>= 1) { v += __shfl_xor(v, o); v2 += __shfl_xor(v2, o); }
      if (lane == 0) redW[wave][s] = make_float2(v, v2);
    }
    __syncthreads();
    if (th < LCH) {
      float s1 = 0.f, s2 = 0.f;
      #pragma unroll
      for (int w = 0; w < 8; ++w) { float2 p = redW[w][th]; s1 += p.x; s2 += p.y; }
      float m = s1 * (1.f / HD_);
      float var = fmaf(-m, m, s2 * (1.f / HD_));
      redF[th] = make_float2(m, rsqrtf(var + 1e-5f));
    }
    __syncthreads();
    const float g = gamma[th], be = beta[th];
    #pragma unroll
    for (int s = 0; s < LCH; ++s) {
      float2 st = redF[s];
      float lnv = (run[s] - st.x) * st.y * g + be;
      float xs = run[s + 1] - run[s];
      int row = wave * 16 + s;
      *(__bf16*)(Alh + swzA(row, dd * 2)) = (__bf16)xs;
      *(__bf16*)(Alh + swzA(row, 128 + dd * 2)) = (__bf16)lnv;
    }
  }
  // No barrier: A-tile rows [wave*16, wave*16+16) written/read by this wave.

  // ---- gates GEMM: single pass, 12 accumulators, A read once per ks ----
  const int arow = wave * 16 + l16;
  f32x4 ai[4], af4[4], ah[4];
  #pragma unroll
  for (int nt = 0; nt < 4; ++nt) {
    ai[nt] = (f32x4){0.f, 0.f, 0.f, 0.f};
    af4[nt] = (f32x4){0.f, 0.f, 0.f, 0.f};
    ah[nt] = (f32x4){0.f, 0.f, 0.f, 0.f};
  }
  #pragma unroll
  for (int ks = 0; ks < 4; ++ks) {
    bf16x8 av = *(const bf16x8*)(Alh + swzA(arow, ks * 64 + quad * 16));
    #pragma unroll
    for (int nt = 0; nt < 4; ++nt) {
      bf16x8 b0 = *(const bf16x8*)(WthL + swzA(nt * 16 + l16, ks * 64 + quad * 16));
      bf16x8 b1 = *(const bf16x8*)(WthL + swzA((4 + nt) * 16 + l16, ks * 64 + quad * 16));
      bf16x8 b2 = *(const bf16x8*)(WthL + swzA((8 + nt) * 16 + l16, ks * 64 + quad * 16));
      ai[nt]  = __builtin_amdgcn_mfma_f32_16x16x32_bf16(av, b0, ai[nt], 0, 0, 0);
      af4[nt] = __builtin_amdgcn_mfma_f32_16x16x32_bf16(av, b1, af4[nt], 0, 0, 0);
      ah[nt]  = __builtin_amdgcn_mfma_f32_16x16x32_bf16(av, b2, ah[nt], 0, 0, 0);
    }
  }
  float fv[16], iv[16];
  #pragma unroll
  for (int nt = 0; nt < 4; ++nt) {
    float bi = bh[nt * 16 + l16], bf_ = bh[64 + nt * 16 + l16], bh_ = bh[128 + nt * 16 + l16];
    #pragma unroll
    for (int r = 0; r < 4; ++r) {
      fv[nt * 4 + r] = sigm(af4[nt][r] + bf_);
      iv[nt * 4 + r] = sigm(ai[nt][r] + bi) * fmaxf(ah[nt][r] + bh_, 0.f);
    }
  }

  // ---- segmented affine scan over s (4 regs x 4 quads) ----
  #pragma unroll
  for (int nt = 0; nt < 4; ++nt) {
    float a = 1.f, bb2 = 0.f, pa[4], pb[4];
    #pragma unroll
    for (int r = 0; r < 4; ++r) {
      float fvv = fv[nt * 4 + r], gvv = iv[nt * 4 + r];
      a = fvv * a;
      bb2 = fmaf(fvv, bb2, gvv);
      pa[r] = a; pb[r] = bb2;
    }
    if constexpr (WRITE_TOT) {
      float TA = 1.f, TB = 0.f;
      #pragma unroll
      for (int q = 0; q < 4; ++q) {
        float Aq = __shfl(a, q * 16 + l16, 64);
        float Bq = __shfl(bb2, q * 16 + l16, 64);
        TB = fmaf(Aq, TB, Bq);
        TA = Aq * TA;
      }
      if (quad == 0) {
        cA[(size_t)cid * HD_ + wave * 64 + nt * 16 + l16] = TA;
        cB[(size_t)cid * HD_ + wave * 64 + nt * 16 + l16] = TB;
      }
    } else {
      float exA = 1.f, exB = 0.f;
      #pragma unroll
      for (int q = 0; q < 3; ++q) {
        float Aq = __shfl(a, q * 16 + l16, 64);
        float Bq = __shfl(bb2, q * 16 + l16, 64);
        if (q < quad) { exB = fmaf(Aq, exB, Bq); exA = Aq * exA; }
      }
      const int dcol = nt * 16 + l16;
      float ci = cin[(size_t)cid * HD_ + wave * 64 + dcol];
      float u = fmaf(exA, ci, exB);
      #pragma unroll
      for (int r = 0; r < 4; ++r) {
        float cv = fmaf(pa[r], u, pb[r]);
        int rowl = wave * 16 + quad * 4 + r;
        *(__bf16*)(Alh + swzA(rowl, 128 + dcol * 2)) = (__bf16)cv;
      }
    }
  }
}

// ---------------- K4: persistent LN + gates GEMM + chunk scan -> cA/cB -------
// 256 blocks x 1024 threads: 2 chunk-lanes x 2 iterations = 4 chunks/block.
__global__ __launch_bounds__(1024) void k_gates_f(const float* __restrict__ x,
                                                  const float* __restrict__ offs,
                                                  const float* __restrict__ gamma,
                                                  const float* __restrict__ beta,
                                                  const __bf16* __restrict__ Wthg,
                                                  const float* __restrict__ bh,
                                                  float* __restrict__ cA,
                                                  float* __restrict__ cB) {
  __shared__ char WthL[192 * 256];        // 48 KB swizzled [n][k]
  __shared__ char Al[2][128 * 256];       // 2 x 32 KB A-tiles
  __shared__ float2 redW[2][8][LCH];
  __shared__ float2 redF[2][LCH];
  const int t = threadIdx.x;
  const int half = t >> 9;

  // stage Wth -> LDS (bf16x8 granules, swizzled)
  #pragma unroll
  for (int i = 0; i < 3; ++i) {
    int g = i * 1024 + t;                 // group-of-8 index, 3072 total
    int n = g >> 4, kb = (g & 15) * 16;
    bf16x8 v = ((const bf16x8*)Wthg)[g];
    *(bf16x8*)(WthL + swzA(n, kb)) = v;
  }
  __syncthreads();

  #pragma unroll 1
  for (int it = 0; it < 2; ++it) {
    const int cid = blockIdx.x * 4 + it * 2 + half;
    chunk_body<true>(x, offs, gamma, beta, bh, Al[half], WthL,
                     redW[half], redF[half], cid, nullptr, cA, cB);
  }
}

// ---------------- 3-level cross-chunk cell scan ------------------------------
__global__ __launch_bounds__(256) void kc_l1(const float* __restrict__ cA,
                                             const float* __restrict__ cB,
                                             float* __restrict__ gA,
                                             float* __restrict__ gB) {
  int w = blockIdx.x * 256 + threadIdx.x;
  int grp = w >> 11, col = w & 2047;
  int b = col >> 9, hd = col & 511;
  float Ag = 1.f, Bg = 0.f;
  #pragma unroll
  for (int i = 0; i < 16; ++i) {
    size_t idx = ((size_t)(b * NCH + grp * 16 + i)) * HD_ + hd;
    float Ac = cA[idx], Bc = cB[idx];
    Bg = fmaf(Ac, Bg, Bc);
    Ag = Ac * Ag;
  }
  gA[grp * NCOL + col] = Ag;
  gB[grp * NCOL + col] = Bg;
}
__global__ __launch_bounds__(256) void kc_l2(float* __restrict__ gA,
                                             const float* __restrict__ gB,
                                             const float* __restrict__ initcx) {
  int col = blockIdx.x * 256 + threadIdx.x;   // 0..2047
  int hd = col & 511;
  float run = initcx[hd];
  #pragma unroll
  for (int g = 0; g < 16; ++g) {
    float Ag = gA[g * NCOL + col], Bg = gB[g * NCOL + col];
    gA[g * NCOL + col] = run;                 // group run-in value
    run = fmaf(Ag, run, Bg);
  }
}
__global__ __launch_bounds__(256) void kc_l3(const float* __restrict__ cA,
                                             const float* __restrict__ cB,
                                             const float* __restrict__ gA,
                                             float* __restrict__ cin) {
  int w = blockIdx.x * 256 + threadIdx.x;
  int grp = w >> 11, col = w & 2047;
  int b = col >> 9, hd = col & 511;
  float run = gA[grp * NCOL + col];
  #pragma unroll
  for (int i = 0; i < 16; ++i) {
    size_t idx = ((size_t)(b * NCH + grp * 16 + i)) * HD_ + hd;
    cin[idx] = run;
    run = fmaf(cA[idx], run, cB[idx]);
  }
}

// ---------------- K6: persistent recompute + cell emit + og GEMM + out -------
__global__ __launch_bounds__(1024) void k_og_f(const float* __restrict__ x,
                                               const float* __restrict__ offs,
                                               const float* __restrict__ gamma,
                                               const float* __restrict__ beta,
                                               const __bf16* __restrict__ Wthg,
                                               const __bf16* __restrict__ Wtog,
                                               const float* __restrict__ bh,
                                               const float* __restrict__ bo,
                                               const float* __restrict__ cin,
                                               float* __restrict__ out) {
  __shared__ char WthL[192 * 256];        // 48 KB
  __shared__ char WtoL[64 * 256];         // 16 KB
  __shared__ char Al[2][128 * 256];       // 64 KB
  __shared__ float2 redW[2][8][LCH];
  __shared__ float2 redF[2][LCH];
  const int t = threadIdx.x;
  const int half = t >> 9;
  const int wave = (t >> 6) & 7;
  const int lane = t & 63, quad = lane >> 4, l16 = lane & 15;

  #pragma unroll
  for (int i = 0; i < 3; ++i) {
    int g = i * 1024 + t;
    int n = g >> 4, kb = (g & 15) * 16;
    bf16x8 v = ((const bf16x8*)Wthg)[g];
    *(bf16x8*)(WthL + swzA(n, kb)) = v;
  }
  {
    int g = t;                            // 1024 groups-of-8 = 8192 elems
    int n = g >> 4, kb = (g & 15) * 16;
    bf16x8 v = ((const bf16x8*)Wtog)[g];
    *(bf16x8*)(WtoL + swzA(n, kb)) = v;
  }
  __syncthreads();

  #pragma unroll 1
  for (int it = 0; it < 2; ++it) {
    const int cid = blockIdx.x * 4 + it * 2 + half;
    const int b = cid >> 8, c = cid & 255;
    chunk_body<false>(x, offs, gamma, beta, bh, Al[half], WthL,
                      redW[half], redF[half], cid, cin, nullptr, nullptr);
    // og GEMM: A = [x | cell], W = WtoL; out = sigm(og)*cell (wave-local rows)
    const int arow = wave * 16 + l16;
    f32x4 acc[4];
    #pragma unroll
    for (int nt = 0; nt < 4; ++nt) acc[nt] = (f32x4){0.f, 0.f, 0.f, 0.f};
    #pragma unroll
    for (int ks = 0; ks < 4; ++ks) {
      bf16x8 av = *(const bf16x8*)(Al[half] + swzA(arow, ks * 64 + quad * 16));
      #pragma unroll
      for (int nt = 0; nt < 4; ++nt) {
        bf16x8 bf_ = *(const bf16x8*)(WtoL + swzA(nt * 16 + l16, ks * 64 + quad * 16));
        acc[nt] = __builtin_amdgcn_mfma_f32_16x16x32_bf16(av, bf_, acc[nt], 0, 0, 0);
      }
    }
    #pragma unroll
    for (int nt = 0; nt < 4; ++nt) {
      const int dcol = nt * 16 + l16;
      float bv = bo[dcol];
      #pragma unroll
      for (int r = 0; r < 4; ++r) {
        int rowl = wave * 16 + quad * 4 + r;
        int s = quad * 4 + r;
        float og = sigm(acc[nt][r] + bv);
        float cv = (float)*(const __bf16*)(Al[half] + swzA(rowl, 128 + dcol * 2));
        out[(((size_t)b * S_ + c * LCH + s) * H_ + wave) * D_ + dcol] = og * cv;
      }
    }
  }
}

extern "C" void kernel_launch(void* const* d_in, const int* in_sizes, int n_in,
                              void* d_out, int out_size, void* d_ws, size_t ws_size,
                              hipStream_t stream) {
  const float* x      = (const float*)d_in[0];
  const float* W_hid  = (const float*)d_in[1];
  const float* b_hid  = (const float*)d_in[2];
  const float* W_og   = (const float*)d_in[3];
  const float* b_og   = (const float*)d_in[4];
  const float* gamma  = (const float*)d_in[5];
  const float* beta   = (const float*)d_in[6];
  const float* initcx = (const float*)d_in[7];
  float* out = (float*)d_out;
  float* ws  = (float*)d_ws;

  // ws layout (floats):
  float*  buf0 = ws;                      // sums -> offs (in place)   524288
  float*  cA   = ws + 524288;             //                           524288
  float*  cB   = cA + 524288;             //                           524288
  float*  cin  = cB + 524288;             //                           524288
  float*  gx   = cin + 524288;            // x-offset group sums        32768
  float*  gA   = gx + 32768;              // cell group compose A       32768
  float*  gB   = gA + 32768;              // cell group compose B       32768
  __bf16* Wth  = (__bf16*)(gB + 32768);   // [192][128] bf16
  __bf16* Wto  = Wth + 24576;             // [64][128] bf16

  k_wt         <<<128,  256, 0, stream>>>(W_hid, W_og, Wth, Wto);
  k_chunk_sums <<<1024, 512, 0, stream>>>(x, buf0);
  kx_l1        <<<128,  256, 0, stream>>>(buf0, gx);
  kx_l2        <<<8,    256, 0, stream>>>(gx);
  kx_l3        <<<128,  256, 0, stream>>>(buf0, gx);
  k_gates_f    <<<256, 1024, 0, stream>>>(x, buf0, gamma, beta, Wth, b_hid, cA, cB);
  kc_l1        <<<128,  256, 0, stream>>>(cA, cB, gA, gB);
  kc_l2        <<<8,    256, 0, stream>>>(gA, gB, initcx);
  kc_l3        <<<128,  256, 0, stream>>>(cA, cB, gA, cin);
  k_og_f       <<<256, 1024, 0, stream>>>(x, buf0, gamma, beta, Wth, Wto,
                                          b_hid, b_og, cin, out);
}

// Round 9
// 205.781 us; speedup vs baseline: 1.2518x; 1.0402x over previous
//
#include <hip/hip_runtime.h>
#include <math.h>

#define S_   4096
#define H_   8
#define D_   64
#define HD_  512
#define NCH  256   // chunks per batch
#define LCH  16    // seq steps per chunk
#define NCOL 2048  // scan columns = B * H * D

typedef __bf16 bf16x8 __attribute__((ext_vector_type(8)));
typedef float  f32x4  __attribute__((ext_vector_type(4)));

__device__ __forceinline__ float sigm(float v) { return 1.f / (1.f + __expf(-v)); }

// XOR-swizzled byte offset into a [rows][128] bf16 LDS tile (row stride 256B).
__device__ __forceinline__ int swzA(int row, int bytecol) {
  return row * 256 + (bytecol ^ ((row & 7) << 4));
}

// ---------------- K0: transpose weights to bf16 [n][k] ----------------
__global__ __launch_bounds__(256) void k_wt(const float* __restrict__ Wh,
                                            const float* __restrict__ Wo,
                                            __bf16* __restrict__ Wth,
                                            __bf16* __restrict__ Wto) {
  int idx = blockIdx.x * 256 + threadIdx.x;   // 0..32767
  if (idx < 24576) {
    int k = idx / 192, n = idx % 192;
    Wth[n * 128 + k] = (__bf16)Wh[idx];
  } else {
    int j = idx - 24576;                       // 0..8191, W_og[k][n], n<64
    int k = j >> 6, n = j & 63;
    Wto[n * 128 + k] = (__bf16)Wo[j];
  }
}

// ---------------- K1: per-chunk sums of x ----------------
__global__ __launch_bounds__(512) void k_chunk_sums(const float* __restrict__ x,
                                                    float* __restrict__ sums) {
  const int b = blockIdx.x >> 8, c = blockIdx.x & 255;
  const int t = threadIdx.x;
  const float* p = x + ((size_t)b * S_ + c * LCH) * HD_ + t;
  float acc = 0.f;
  #pragma unroll
  for (int i = 0; i < LCH; ++i) acc += p[(size_t)i * HD_];
  sums[((size_t)b * NCH + c) * HD_ + t] = acc;
}

// ---------------- 3-level exclusive scan of chunk sums (x offsets) -----------
__global__ __launch_bounds__(256) void kx_l1(const float* __restrict__ sums,
                                             float* __restrict__ gx) {
  int w = blockIdx.x * 256 + threadIdx.x;    // 0..32767
  int grp = w >> 11, col = w & 2047;
  int b = col >> 9, hd = col & 511;
  float s = 0.f;
  #pragma unroll
  for (int i = 0; i < 16; ++i)
    s += sums[((size_t)(b * NCH + grp * 16 + i)) * HD_ + hd];
  gx[grp * NCOL + col] = s;
}
__global__ __launch_bounds__(256) void kx_l2(float* __restrict__ gx) {
  int col = blockIdx.x * 256 + threadIdx.x;  // 0..2047
  float run = 0.f;
  #pragma unroll
  for (int g = 0; g < 16; ++g) {
    float v = gx[g * NCOL + col];
    gx[g * NCOL + col] = run;
    run += v;
  }
}
__global__ __launch_bounds__(256) void kx_l3(float* __restrict__ sums,
                                             const float* __restrict__ gx) {
  int w = blockIdx.x * 256 + threadIdx.x;
  int grp = w >> 11, col = w & 2047;
  int b = col >> 9, hd = col & 511;
  float run = gx[grp * NCOL + col];
  #pragma unroll
  for (int i = 0; i < 16; ++i) {
    size_t idx = ((size_t)(b * NCH + grp * 16 + i)) * HD_ + hd;
    float v = sums[idx];
    sums[idx] = run;
    run += v;
  }
}

// -------- per-chunk body: LN -> LDS A-tile, 3-pass gates GEMM, chunk scan ----
// Runs on one 512-thread half (8 waves, wave = head). Weights read from LDS.
// 3-pass GEMM keeps only 4 MFMA accumulators live (register-lean; the
// 12-acc single-pass variant spilled under the 1024-thread 128-reg cap).
// WRITE_TOT=true : write per-chunk scan totals cA/cB.
// WRITE_TOT=false: fused cell-emit (needs cin) -> bf16 cell into A-tile.
template <bool WRITE_TOT>
__device__ __forceinline__ void chunk_body(const float* __restrict__ x,
                                           const float* __restrict__ offs,
                                           const float* __restrict__ gamma,
                                           const float* __restrict__ beta,
                                           const float* __restrict__ bh,
                                           char* Alh, const char* WthL,
                                           float2 (*redW)[LCH],   // [8][16]
                                           float2* redF,          // [16]
                                           int cid,
                                           const float* __restrict__ cin,
                                           float* __restrict__ cA,
                                           float* __restrict__ cB) {
  const int t = threadIdx.x;
  const int th = t & 511;                 // column within chunk
  const int wave = (t >> 6) & 7;          // head
  const int lane = t & 63, quad = lane >> 4, l16 = lane & 15;
  const int b = cid >> 8, c = cid & 255;

  // ---- LN: column-parallel, one two-level reduction ----
  {
    const int dd = th & 63;
    const float* xp = x + ((size_t)b * S_ + c * LCH) * HD_ + th;
    float run[LCH + 1];
    run[0] = offs[(size_t)cid * HD_ + th];
    #pragma unroll
    for (int s = 0; s < LCH; ++s) run[s + 1] = run[s] + xp[(size_t)s * HD_];
    #pragma unroll
    for (int s = 0; s < LCH; ++s) {
      float v = run[s], v2 = run[s] * run[s];
      #pragma unroll
      for (int o = 32; o; o >>= 1) { v += __shfl_xor(v, o); v2 += __shfl_xor(v2, o); }
      if (lane == 0) redW[wave][s] = make_float2(v, v2);
    }
    __syncthreads();
    if (th < LCH) {
      float s1 = 0.f, s2 = 0.f;
      #pragma unroll
      for (int w = 0; w < 8; ++w) { float2 p = redW[w][th]; s1 += p.x; s2 += p.y; }
      float m = s1 * (1.f / HD_);
      float var = fmaf(-m, m, s2 * (1.f / HD_));
      redF[th] = make_float2(m, rsqrtf(var + 1e-5f));
    }
    __syncthreads();
    const float g = gamma[th], be = beta[th];
    #pragma unroll
    for (int s = 0; s < LCH; ++s) {
      float2 st = redF[s];
      float lnv = (run[s] - st.x) * st.y * g + be;
      float xs = run[s + 1] - run[s];
      int row = wave * 16 + s;
      *(__bf16*)(Alh + swzA(row, dd * 2)) = (__bf16)xs;
      *(__bf16*)(Alh + swzA(row, 128 + dd * 2)) = (__bf16)lnv;
    }
  }
  // No barrier: A-tile rows [wave*16, wave*16+16) written/read by this wave.

  // ---- gates GEMM: 3 register-lean N-passes (F, I, H) ----
  const int arow = wave * 16 + l16;
  float fv[16], iv[16];
  // pass F (weight rows 64..127)
  {
    f32x4 acc[4];
    #pragma unroll
    for (int nt = 0; nt < 4; ++nt) acc[nt] = (f32x4){0.f, 0.f, 0.f, 0.f};
    #pragma unroll
    for (int ks = 0; ks < 4; ++ks) {
      bf16x8 av = *(const bf16x8*)(Alh + swzA(arow, ks * 64 + quad * 16));
      #pragma unroll
      for (int nt = 0; nt < 4; ++nt) {
        bf16x8 bf_ = *(const bf16x8*)(WthL + swzA((4 + nt) * 16 + l16, ks * 64 + quad * 16));
        acc[nt] = __builtin_amdgcn_mfma_f32_16x16x32_bf16(av, bf_, acc[nt], 0, 0, 0);
      }
    }
    #pragma unroll
    for (int nt = 0; nt < 4; ++nt) {
      float bf_ = bh[64 + nt * 16 + l16];
      #pragma unroll
      for (int r = 0; r < 4; ++r) fv[nt * 4 + r] = sigm(acc[nt][r] + bf_);
    }
  }
  // pass I (weight rows 0..63)
  {
    f32x4 acc[4];
    #pragma unroll
    for (int nt = 0; nt < 4; ++nt) acc[nt] = (f32x4){0.f, 0.f, 0.f, 0.f};
    #pragma unroll
    for (int ks = 0; ks < 4; ++ks) {
      bf16x8 av = *(const bf16x8*)(Alh + swzA(arow, ks * 64 + quad * 16));
      #pragma unroll
      for (int nt = 0; nt < 4; ++nt) {
        bf16x8 bf_ = *(const bf16x8*)(WthL + swzA(nt * 16 + l16, ks * 64 + quad * 16));
        acc[nt] = __builtin_amdgcn_mfma_f32_16x16x32_bf16(av, bf_, acc[nt], 0, 0, 0);
      }
    }
    #pragma unroll
    for (int nt = 0; nt < 4; ++nt) {
      float bi = bh[nt * 16 + l16];
      #pragma unroll
      for (int r = 0; r < 4; ++r) iv[nt * 4 + r] = sigm(acc[nt][r] + bi);
    }
  }
  // pass H (weight rows 128..191): iv becomes g = sigm(i)*relu(h)
  {
    f32x4 acc[4];
    #pragma unroll
    for (int nt = 0; nt < 4; ++nt) acc[nt] = (f32x4){0.f, 0.f, 0.f, 0.f};
    #pragma unroll
    for (int ks = 0; ks < 4; ++ks) {
      bf16x8 av = *(const bf16x8*)(Alh + swzA(arow, ks * 64 + quad * 16));
      #pragma unroll
      for (int nt = 0; nt < 4; ++nt) {
        bf16x8 bf_ = *(const bf16x8*)(WthL + swzA((8 + nt) * 16 + l16, ks * 64 + quad * 16));
        acc[nt] = __builtin_amdgcn_mfma_f32_16x16x32_bf16(av, bf_, acc[nt], 0, 0, 0);
      }
    }
    #pragma unroll
    for (int nt = 0; nt < 4; ++nt) {
      float bh_ = bh[128 + nt * 16 + l16];
      #pragma unroll
      for (int r = 0; r < 4; ++r)
        iv[nt * 4 + r] = iv[nt * 4 + r] * fmaxf(acc[nt][r] + bh_, 0.f);
    }
  }

  // ---- segmented affine scan over s (4 regs x 4 quads) ----
  #pragma unroll
  for (int nt = 0; nt < 4; ++nt) {
    float a = 1.f, bb2 = 0.f, pa[4], pb[4];
    #pragma unroll
    for (int r = 0; r < 4; ++r) {
      float fvv = fv[nt * 4 + r], gvv = iv[nt * 4 + r];
      a = fvv * a;
      bb2 = fmaf(fvv, bb2, gvv);
      pa[r] = a; pb[r] = bb2;
    }
    if constexpr (WRITE_TOT) {
      float TA = 1.f, TB = 0.f;
      #pragma unroll
      for (int q = 0; q < 4; ++q) {
        float Aq = __shfl(a, q * 16 + l16, 64);
        float Bq = __shfl(bb2, q * 16 + l16, 64);
        TB = fmaf(Aq, TB, Bq);
        TA = Aq * TA;
      }
      if (quad == 0) {
        cA[(size_t)cid * HD_ + wave * 64 + nt * 16 + l16] = TA;
        cB[(size_t)cid * HD_ + wave * 64 + nt * 16 + l16] = TB;
      }
    } else {
      float exA = 1.f, exB = 0.f;
      #pragma unroll
      for (int q = 0; q < 3; ++q) {
        float Aq = __shfl(a, q * 16 + l16, 64);
        float Bq = __shfl(bb2, q * 16 + l16, 64);
        if (q < quad) { exB = fmaf(Aq, exB, Bq); exA = Aq * exA; }
      }
      const int dcol = nt * 16 + l16;
      float ci = cin[(size_t)cid * HD_ + wave * 64 + dcol];
      float u = fmaf(exA, ci, exB);
      #pragma unroll
      for (int r = 0; r < 4; ++r) {
        float cv = fmaf(pa[r], u, pb[r]);
        int rowl = wave * 16 + quad * 4 + r;
        *(__bf16*)(Alh + swzA(rowl, 128 + dcol * 2)) = (__bf16)cv;
      }
    }
  }
}

// ---------------- K4: persistent LN + gates GEMM + chunk scan -> cA/cB -------
// 256 blocks x 1024 threads: 2 chunk-lanes x 2 iterations = 4 chunks/block.
__global__ __launch_bounds__(1024, 4) void k_gates_f(const float* __restrict__ x,
                                                     const float* __restrict__ offs,
                                                     const float* __restrict__ gamma,
                                                     const float* __restrict__ beta,
                                                     const __bf16* __restrict__ Wthg,
                                                     const float* __restrict__ bh,
                                                     float* __restrict__ cA,
                                                     float* __restrict__ cB) {
  __shared__ char WthL[192 * 256];        // 48 KB swizzled [n][k]
  __shared__ char Al[2][128 * 256];       // 2 x 32 KB A-tiles
  __shared__ float2 redW[2][8][LCH];
  __shared__ float2 redF[2][LCH];
  const int t = threadIdx.x;
  const int half = t >> 9;

  // stage Wth -> LDS (bf16x8 granules, swizzled)
  #pragma unroll
  for (int i = 0; i < 3; ++i) {
    int g = i * 1024 + t;                 // group-of-8 index, 3072 total
    int n = g >> 4, kb = (g & 15) * 16;
    bf16x8 v = ((const bf16x8*)Wthg)[g];
    *(bf16x8*)(WthL + swzA(n, kb)) = v;
  }
  __syncthreads();

  #pragma unroll 1
  for (int it = 0; it < 2; ++it) {
    const int cid = blockIdx.x * 4 + it * 2 + half;
    chunk_body<true>(x, offs, gamma, beta, bh, Al[half], WthL,
                     redW[half], redF[half], cid, nullptr, cA, cB);
  }
}

// ---------------- 3-level cross-chunk cell scan ------------------------------
__global__ __launch_bounds__(256) void kc_l1(const float* __restrict__ cA,
                                             const float* __restrict__ cB,
                                             float* __restrict__ gA,
                                             float* __restrict__ gB) {
  int w = blockIdx.x * 256 + threadIdx.x;
  int grp = w >> 11, col = w & 2047;
  int b = col >> 9, hd = col & 511;
  float Ag = 1.f, Bg = 0.f;
  #pragma unroll
  for (int i = 0; i < 16; ++i) {
    size_t idx = ((size_t)(b * NCH + grp * 16 + i)) * HD_ + hd;
    float Ac = cA[idx], Bc = cB[idx];
    Bg = fmaf(Ac, Bg, Bc);
    Ag = Ac * Ag;
  }
  gA[grp * NCOL + col] = Ag;
  gB[grp * NCOL + col] = Bg;
}
__global__ __launch_bounds__(256) void kc_l2(float* __restrict__ gA,
                                             const float* __restrict__ gB,
                                             const float* __restrict__ initcx) {
  int col = blockIdx.x * 256 + threadIdx.x;   // 0..2047
  int hd = col & 511;
  float run = initcx[hd];
  #pragma unroll
  for (int g = 0; g < 16; ++g) {
    float Ag = gA[g * NCOL + col], Bg = gB[g * NCOL + col];
    gA[g * NCOL + col] = run;                 // group run-in value
    run = fmaf(Ag, run, Bg);
  }
}
__global__ __launch_bounds__(256) void kc_l3(const float* __restrict__ cA,
                                             const float* __restrict__ cB,
                                             const float* __restrict__ gA,
                                             float* __restrict__ cin) {
  int w = blockIdx.x * 256 + threadIdx.x;
  int grp = w >> 11, col = w & 2047;
  int b = col >> 9, hd = col & 511;
  float run = gA[grp * NCOL + col];
  #pragma unroll
  for (int i = 0; i < 16; ++i) {
    size_t idx = ((size_t)(b * NCH + grp * 16 + i)) * HD_ + hd;
    cin[idx] = run;
    run = fmaf(cA[idx], run, cB[idx]);
  }
}

// ---------------- K6: persistent recompute + cell emit + og GEMM + out -------
__global__ __launch_bounds__(1024, 4) void k_og_f(const float* __restrict__ x,
                                                  const float* __restrict__ offs,
                                                  const float* __restrict__ gamma,
                                                  const float* __restrict__ beta,
                                                  const __bf16* __restrict__ Wthg,
                                                  const __bf16* __restrict__ Wtog,
                                                  const float* __restrict__ bh,
                                                  const float* __restrict__ bo,
                                                  const float* __restrict__ cin,
                                                  float* __restrict__ out) {
  __shared__ char WthL[192 * 256];        // 48 KB
  __shared__ char WtoL[64 * 256];         // 16 KB
  __shared__ char Al[2][128 * 256];       // 64 KB
  __shared__ float2 redW[2][8][LCH];
  __shared__ float2 redF[2][LCH];
  const int t = threadIdx.x;
  const int half = t >> 9;
  const int wave = (t >> 6) & 7;
  const int lane = t & 63, quad = lane >> 4, l16 = lane & 15;

  #pragma unroll
  for (int i = 0; i < 3; ++i) {
    int g = i * 1024 + t;
    int n = g >> 4, kb = (g & 15) * 16;
    bf16x8 v = ((const bf16x8*)Wthg)[g];
    *(bf16x8*)(WthL + swzA(n, kb)) = v;
  }
  {
    int g = t;                            // 1024 groups-of-8 = 8192 elems
    int n = g >> 4, kb = (g & 15) * 16;
    bf16x8 v = ((const bf16x8*)Wtog)[g];
    *(bf16x8*)(WtoL + swzA(n, kb)) = v;
  }
  __syncthreads();

  #pragma unroll 1
  for (int it = 0; it < 2; ++it) {
    const int cid = blockIdx.x * 4 + it * 2 + half;
    const int b = cid >> 8, c = cid & 255;
    chunk_body<false>(x, offs, gamma, beta, bh, Al[half], WthL,
                      redW[half], redF[half], cid, cin, nullptr, nullptr);
    // og GEMM: A = [x | cell], W = WtoL; out = sigm(og)*cell (wave-local rows)
    const int arow = wave * 16 + l16;
    f32x4 acc[4];
    #pragma unroll
    for (int nt = 0; nt < 4; ++nt) acc[nt] = (f32x4){0.f, 0.f, 0.f, 0.f};
    #pragma unroll
    for (int ks = 0; ks < 4; ++ks) {
      bf16x8 av = *(const bf16x8*)(Al[half] + swzA(arow, ks * 64 + quad * 16));
      #pragma unroll
      for (int nt = 0; nt < 4; ++nt) {
        bf16x8 bf_ = *(const bf16x8*)(WtoL + swzA(nt * 16 + l16, ks * 64 + quad * 16));
        acc[nt] = __builtin_amdgcn_mfma_f32_16x16x32_bf16(av, bf_, acc[nt], 0, 0, 0);
      }
    }
    #pragma unroll
    for (int nt = 0; nt < 4; ++nt) {
      const int dcol = nt * 16 + l16;
      float bv = bo[dcol];
      #pragma unroll
      for (int r = 0; r < 4; ++r) {
        int rowl = wave * 16 + quad * 4 + r;
        int s = quad * 4 + r;
        float og = sigm(acc[nt][r] + bv);
        float cv = (float)*(const __bf16*)(Al[half] + swzA(rowl, 128 + dcol * 2));
        out[(((size_t)b * S_ + c * LCH + s) * H_ + wave) * D_ + dcol] = og * cv;
      }
    }
  }
}

extern "C" void kernel_launch(void* const* d_in, const int* in_sizes, int n_in,
                              void* d_out, int out_size, void* d_ws, size_t ws_size,
                              hipStream_t stream) {
  const float* x      = (const float*)d_in[0];
  const float* W_hid  = (const float*)d_in[1];
  const float* b_hid  = (const float*)d_in[2];
  const float* W_og   = (const float*)d_in[3];
  const float* b_og   = (const float*)d_in[4];
  const float* gamma  = (const float*)d_in[5];
  const float* beta   = (const float*)d_in[6];
  const float* initcx = (const float*)d_in[7];
  float* out = (float*)d_out;
  float* ws  = (float*)d_ws;

  // ws layout (floats):
  float*  buf0 = ws;                      // sums -> offs (in place)   524288
  float*  cA   = ws + 524288;             //                           524288
  float*  cB   = cA + 524288;             //                           524288
  float*  cin  = cB + 524288;             //                           524288
  float*  gx   = cin + 524288;            // x-offset group sums        32768
  float*  gA   = gx + 32768;              // cell group compose A       32768
  float*  gB   = gA + 32768;              // cell group compose B       32768
  __bf16* Wth  = (__bf16*)(gB + 32768);   // [192][128] bf16
  __bf16* Wto  = Wth + 24576;             // [64][128] bf16

  k_wt         <<<128,  256, 0, stream>>>(W_hid, W_og, Wth, Wto);
  k_chunk_sums <<<1024, 512, 0, stream>>>(x, buf0);
  kx_l1        <<<128,  256, 0, stream>>>(buf0, gx);
  kx_l2        <<<8,    256, 0, stream>>>(gx);
  kx_l3        <<<128,  256, 0, stream>>>(buf0, gx);
  k_gates_f    <<<256, 1024, 0, stream>>>(x, buf0, gamma, beta, Wth, b_hid, cA, cB);
  kc_l1        <<<128,  256, 0, stream>>>(cA, cB, gA, gB);
  kc_l2        <<<8,    256, 0, stream>>>(gA, gB, initcx);
  kc_l3        <<<128,  256, 0, stream>>>(cA, cB, gA, cin);
  k_og_f       <<<256, 1024, 0, stream>>>(x, buf0, gamma, beta, Wth, Wto,
                                          b_hid, b_og, cin, out);
}

// Round 10
// 200.735 us; speedup vs baseline: 1.2832x; 1.0251x over previous
//
#include <hip/hip_runtime.h>
#include <math.h>

#define S_   4096
#define H_   8
#define D_   64
#define HD_  512
#define NCH  256   // chunks per batch
#define LCH  16    // seq steps per chunk
#define NCOL 2048  // scan columns = B * H * D

typedef __bf16 bf16x8 __attribute__((ext_vector_type(8)));
typedef float  f32x4  __attribute__((ext_vector_type(4)));

__device__ __forceinline__ float sigm(float v) { return 1.f / (1.f + __expf(-v)); }

// XOR-swizzled byte offset into a [rows][128] bf16 LDS tile (row stride 256B).
__device__ __forceinline__ int swzA(int row, int bytecol) {
  return row * 256 + (bytecol ^ ((row & 7) << 4));
}

// ---------------- K0: transpose weights to bf16 [n][k] ----------------
__global__ __launch_bounds__(256) void k_wt(const float* __restrict__ Wh,
                                            const float* __restrict__ Wo,
                                            __bf16* __restrict__ Wth,
                                            __bf16* __restrict__ Wto) {
  int idx = blockIdx.x * 256 + threadIdx.x;   // 0..32767
  if (idx < 24576) {
    int k = idx / 192, n = idx % 192;
    Wth[n * 128 + k] = (__bf16)Wh[idx];
  } else {
    int j = idx - 24576;                       // 0..8191, W_og[k][n], n<64
    int k = j >> 6, n = j & 63;
    Wto[n * 128 + k] = (__bf16)Wo[j];
  }
}

// ---------------- K1: per-chunk sums of x ----------------
__global__ __launch_bounds__(512) void k_chunk_sums(const float* __restrict__ x,
                                                    float* __restrict__ sums) {
  const int b = blockIdx.x >> 8, c = blockIdx.x & 255;
  const int t = threadIdx.x;
  const float* p = x + ((size_t)b * S_ + c * LCH) * HD_ + t;
  float acc = 0.f;
  #pragma unroll
  for (int i = 0; i < LCH; ++i) acc += p[(size_t)i * HD_];
  sums[((size_t)b * NCH + c) * HD_ + t] = acc;
}

// ---------------- 3-level exclusive scan of chunk sums (x offsets) -----------
__global__ __launch_bounds__(256) void kx_l1(const float* __restrict__ sums,
                                             float* __restrict__ gx) {
  int w = blockIdx.x * 256 + threadIdx.x;    // 0..32767
  int grp = w >> 11, col = w & 2047;
  int b = col >> 9, hd = col & 511;
  float s = 0.f;
  #pragma unroll
  for (int i = 0; i < 16; ++i)
    s += sums[((size_t)(b * NCH + grp * 16 + i)) * HD_ + hd];
  gx[grp * NCOL + col] = s;
}
__global__ __launch_bounds__(256) void kx_l2(float* __restrict__ gx) {
  int col = blockIdx.x * 256 + threadIdx.x;  // 0..2047
  float run = 0.f;
  #pragma unroll
  for (int g = 0; g < 16; ++g) {
    float v = gx[g * NCOL + col];
    gx[g * NCOL + col] = run;
    run += v;
  }
}
__global__ __launch_bounds__(256) void kx_l3(float* __restrict__ sums,
                                             const float* __restrict__ gx) {
  int w = blockIdx.x * 256 + threadIdx.x;
  int grp = w >> 11, col = w & 2047;
  int b = col >> 9, hd = col & 511;
  float run = gx[grp * NCOL + col];
  #pragma unroll
  for (int i = 0; i < 16; ++i) {
    size_t idx = ((size_t)(b * NCH + grp * 16 + i)) * HD_ + hd;
    float v = sums[idx];
    sums[idx] = run;
    run += v;
  }
}

// -------- per-chunk body: LN -> LDS A-tile, 3-pass gates GEMM, chunk scan ----
// Runs on one 512-thread half (8 waves, wave = head). Weights read from LDS.
// Pass order I -> H -> F with the affine scan fused into pass F per nt-group:
// only iv[16] persists across passes (no fv[16] array) — register diet so the
// body fits even a 64-arch-VGPR budget without memory scratch.
// WRITE_TOT=true : write per-chunk scan totals cA/cB.
// WRITE_TOT=false: fused cell-emit (needs cin) -> bf16 cell into A-tile.
template <bool WRITE_TOT>
__device__ __forceinline__ void chunk_body(const float* __restrict__ x,
                                           const float* __restrict__ offs,
                                           const float* __restrict__ gamma,
                                           const float* __restrict__ beta,
                                           const float* __restrict__ bh,
                                           char* Alh, const char* WthL,
                                           float2 (*redW)[LCH],   // [8][16]
                                           float2* redF,          // [16]
                                           int cid,
                                           const float* __restrict__ cin,
                                           float* __restrict__ cA,
                                           float* __restrict__ cB) {
  const int t = threadIdx.x;
  const int th = t & 511;                 // column within chunk
  const int wave = (t >> 6) & 7;          // head
  const int lane = t & 63, quad = lane >> 4, l16 = lane & 15;
  const int b = cid >> 8, c = cid & 255;

  // ---- LN: column-parallel, one two-level reduction ----
  {
    const int dd = th & 63;
    const float* xp = x + ((size_t)b * S_ + c * LCH) * HD_ + th;
    float run[LCH + 1];
    run[0] = offs[(size_t)cid * HD_ + th];
    #pragma unroll
    for (int s = 0; s < LCH; ++s) run[s + 1] = run[s] + xp[(size_t)s * HD_];
    #pragma unroll
    for (int s = 0; s < LCH; ++s) {
      float v = run[s], v2 = run[s] * run[s];
      #pragma unroll
      for (int o = 32; o; o >>= 1) { v += __shfl_xor(v, o); v2 += __shfl_xor(v2, o); }
      if (lane == 0) redW[wave][s] = make_float2(v, v2);
    }
    __syncthreads();
    if (th < LCH) {
      float s1 = 0.f, s2 = 0.f;
      #pragma unroll
      for (int w = 0; w < 8; ++w) { float2 p = redW[w][th]; s1 += p.x; s2 += p.y; }
      float m = s1 * (1.f / HD_);
      float var = fmaf(-m, m, s2 * (1.f / HD_));
      redF[th] = make_float2(m, rsqrtf(var + 1e-5f));
    }
    __syncthreads();
    const float g = gamma[th], be = beta[th];
    #pragma unroll
    for (int s = 0; s < LCH; ++s) {
      float2 st = redF[s];
      float lnv = (run[s] - st.x) * st.y * g + be;
      float xs = run[s + 1] - run[s];
      int row = wave * 16 + s;
      *(__bf16*)(Alh + swzA(row, dd * 2)) = (__bf16)xs;
      *(__bf16*)(Alh + swzA(row, 128 + dd * 2)) = (__bf16)lnv;
    }
  }
  // No barrier: A-tile rows [wave*16, wave*16+16) written/read by this wave.

  const int arow = wave * 16 + l16;
  float iv[16];
  // pass I (weight rows 0..63): iv = sigm(i)
  {
    f32x4 acc[4];
    #pragma unroll
    for (int nt = 0; nt < 4; ++nt) acc[nt] = (f32x4){0.f, 0.f, 0.f, 0.f};
    #pragma unroll
    for (int ks = 0; ks < 4; ++ks) {
      bf16x8 av = *(const bf16x8*)(Alh + swzA(arow, ks * 64 + quad * 16));
      #pragma unroll
      for (int nt = 0; nt < 4; ++nt) {
        bf16x8 bf_ = *(const bf16x8*)(WthL + swzA(nt * 16 + l16, ks * 64 + quad * 16));
        acc[nt] = __builtin_amdgcn_mfma_f32_16x16x32_bf16(av, bf_, acc[nt], 0, 0, 0);
      }
    }
    #pragma unroll
    for (int nt = 0; nt < 4; ++nt) {
      float bi = bh[nt * 16 + l16];
      #pragma unroll
      for (int r = 0; r < 4; ++r) iv[nt * 4 + r] = sigm(acc[nt][r] + bi);
    }
  }
  // pass H (weight rows 128..191): iv *= relu(h)
  {
    f32x4 acc[4];
    #pragma unroll
    for (int nt = 0; nt < 4; ++nt) acc[nt] = (f32x4){0.f, 0.f, 0.f, 0.f};
    #pragma unroll
    for (int ks = 0; ks < 4; ++ks) {
      bf16x8 av = *(const bf16x8*)(Alh + swzA(arow, ks * 64 + quad * 16));
      #pragma unroll
      for (int nt = 0; nt < 4; ++nt) {
        bf16x8 bf_ = *(const bf16x8*)(WthL + swzA((8 + nt) * 16 + l16, ks * 64 + quad * 16));
        acc[nt] = __builtin_amdgcn_mfma_f32_16x16x32_bf16(av, bf_, acc[nt], 0, 0, 0);
      }
    }
    #pragma unroll
    for (int nt = 0; nt < 4; ++nt) {
      float bh_ = bh[128 + nt * 16 + l16];
      #pragma unroll
      for (int r = 0; r < 4; ++r)
        iv[nt * 4 + r] = iv[nt * 4 + r] * fmaxf(acc[nt][r] + bh_, 0.f);
    }
  }
  // pass F (weight rows 64..127) + fused segmented affine scan per nt-group
  {
    f32x4 acc[4];
    #pragma unroll
    for (int nt = 0; nt < 4; ++nt) acc[nt] = (f32x4){0.f, 0.f, 0.f, 0.f};
    #pragma unroll
    for (int ks = 0; ks < 4; ++ks) {
      bf16x8 av = *(const bf16x8*)(Alh + swzA(arow, ks * 64 + quad * 16));
      #pragma unroll
      for (int nt = 0; nt < 4; ++nt) {
        bf16x8 bf_ = *(const bf16x8*)(WthL + swzA((4 + nt) * 16 + l16, ks * 64 + quad * 16));
        acc[nt] = __builtin_amdgcn_mfma_f32_16x16x32_bf16(av, bf_, acc[nt], 0, 0, 0);
      }
    }
    #pragma unroll
    for (int nt = 0; nt < 4; ++nt) {
      float bf_ = bh[64 + nt * 16 + l16];
      float a = 1.f, bb2 = 0.f, pa[4], pb[4];
      #pragma unroll
      for (int r = 0; r < 4; ++r) {
        float fvv = sigm(acc[nt][r] + bf_);
        float gvv = iv[nt * 4 + r];
        a = fvv * a;
        bb2 = fmaf(fvv, bb2, gvv);
        pa[r] = a; pb[r] = bb2;
      }
      if constexpr (WRITE_TOT) {
        float TA = 1.f, TB = 0.f;
        #pragma unroll
        for (int q = 0; q < 4; ++q) {
          float Aq = __shfl(a, q * 16 + l16, 64);
          float Bq = __shfl(bb2, q * 16 + l16, 64);
          TB = fmaf(Aq, TB, Bq);
          TA = Aq * TA;
        }
        if (quad == 0) {
          cA[(size_t)cid * HD_ + wave * 64 + nt * 16 + l16] = TA;
          cB[(size_t)cid * HD_ + wave * 64 + nt * 16 + l16] = TB;
        }
      } else {
        float exA = 1.f, exB = 0.f;
        #pragma unroll
        for (int q = 0; q < 3; ++q) {
          float Aq = __shfl(a, q * 16 + l16, 64);
          float Bq = __shfl(bb2, q * 16 + l16, 64);
          if (q < quad) { exB = fmaf(Aq, exB, Bq); exA = Aq * exA; }
        }
        const int dcol = nt * 16 + l16;
        float ci = cin[(size_t)cid * HD_ + wave * 64 + dcol];
        float u = fmaf(exA, ci, exB);
        #pragma unroll
        for (int r = 0; r < 4; ++r) {
          float cv = fmaf(pa[r], u, pb[r]);
          int rowl = wave * 16 + quad * 4 + r;
          *(__bf16*)(Alh + swzA(rowl, 128 + dcol * 2)) = (__bf16)cv;
        }
      }
    }
  }
}

// ---------------- K4: persistent LN + gates GEMM + chunk scan -> cA/cB -------
// 256 blocks x 1024 threads: 2 chunk-lanes x 2 iterations = 4 chunks/block.
// waves_per_eu(4,4): LDS caps us at 1 block/CU (4 waves/EU) anyway — stop the
// allocator from shrinking to 64 regs for an occupancy it can never get.
__global__ __launch_bounds__(1024)
__attribute__((amdgpu_waves_per_eu(4, 4)))
void k_gates_f(const float* __restrict__ x,
               const float* __restrict__ offs,
               const float* __restrict__ gamma,
               const float* __restrict__ beta,
               const __bf16* __restrict__ Wthg,
               const float* __restrict__ bh,
               float* __restrict__ cA,
               float* __restrict__ cB) {
  __shared__ char WthL[192 * 256];        // 48 KB swizzled [n][k]
  __shared__ char Al[2][128 * 256];       // 2 x 32 KB A-tiles
  __shared__ float2 redW[2][8][LCH];
  __shared__ float2 redF[2][LCH];
  const int t = threadIdx.x;
  const int half = t >> 9;

  // stage Wth -> LDS (bf16x8 granules, swizzled)
  #pragma unroll
  for (int i = 0; i < 3; ++i) {
    int g = i * 1024 + t;                 // group-of-8 index, 3072 total
    int n = g >> 4, kb = (g & 15) * 16;
    bf16x8 v = ((const bf16x8*)Wthg)[g];
    *(bf16x8*)(WthL + swzA(n, kb)) = v;
  }
  __syncthreads();

  #pragma unroll 1
  for (int it = 0; it < 2; ++it) {
    const int cid = blockIdx.x * 4 + it * 2 + half;
    chunk_body<true>(x, offs, gamma, beta, bh, Al[half], WthL,
                     redW[half], redF[half], cid, nullptr, cA, cB);
  }
}

// ---------------- 3-level cross-chunk cell scan ------------------------------
__global__ __launch_bounds__(256) void kc_l1(const float* __restrict__ cA,
                                             const float* __restrict__ cB,
                                             float* __restrict__ gA,
                                             float* __restrict__ gB) {
  int w = blockIdx.x * 256 + threadIdx.x;
  int grp = w >> 11, col = w & 2047;
  int b = col >> 9, hd = col & 511;
  float Ag = 1.f, Bg = 0.f;
  #pragma unroll
  for (int i = 0; i < 16; ++i) {
    size_t idx = ((size_t)(b * NCH + grp * 16 + i)) * HD_ + hd;
    float Ac = cA[idx], Bc = cB[idx];
    Bg = fmaf(Ac, Bg, Bc);
    Ag = Ac * Ag;
  }
  gA[grp * NCOL + col] = Ag;
  gB[grp * NCOL + col] = Bg;
}
__global__ __launch_bounds__(256) void kc_l2(float* __restrict__ gA,
                                             const float* __restrict__ gB,
                                             const float* __restrict__ initcx) {
  int col = blockIdx.x * 256 + threadIdx.x;   // 0..2047
  int hd = col & 511;
  float run = initcx[hd];
  #pragma unroll
  for (int g = 0; g < 16; ++g) {
    float Ag = gA[g * NCOL + col], Bg = gB[g * NCOL + col];
    gA[g * NCOL + col] = run;                 // group run-in value
    run = fmaf(Ag, run, Bg);
  }
}
__global__ __launch_bounds__(256) void kc_l3(const float* __restrict__ cA,
                                             const float* __restrict__ cB,
                                             const float* __restrict__ gA,
                                             float* __restrict__ cin) {
  int w = blockIdx.x * 256 + threadIdx.x;
  int grp = w >> 11, col = w & 2047;
  int b = col >> 9, hd = col & 511;
  float run = gA[grp * NCOL + col];
  #pragma unroll
  for (int i = 0; i < 16; ++i) {
    size_t idx = ((size_t)(b * NCH + grp * 16 + i)) * HD_ + hd;
    cin[idx] = run;
    run = fmaf(cA[idx], run, cB[idx]);
  }
}

// ---------------- K6: persistent recompute + cell emit + og GEMM + out -------
__global__ __launch_bounds__(1024)
__attribute__((amdgpu_waves_per_eu(4, 4)))
void k_og_f(const float* __restrict__ x,
            const float* __restrict__ offs,
            const float* __restrict__ gamma,
            const float* __restrict__ beta,
            const __bf16* __restrict__ Wthg,
            const __bf16* __restrict__ Wtog,
            const float* __restrict__ bh,
            const float* __restrict__ bo,
            const float* __restrict__ cin,
            float* __restrict__ out) {
  __shared__ char WthL[192 * 256];        // 48 KB
  __shared__ char WtoL[64 * 256];         // 16 KB
  __shared__ char Al[2][128 * 256];       // 64 KB
  __shared__ float2 redW[2][8][LCH];
  __shared__ float2 redF[2][LCH];
  const int t = threadIdx.x;
  const int half = t >> 9;
  const int wave = (t >> 6) & 7;
  const int lane = t & 63, quad = lane >> 4, l16 = lane & 15;

  #pragma unroll
  for (int i = 0; i < 3; ++i) {
    int g = i * 1024 + t;
    int n = g >> 4, kb = (g & 15) * 16;
    bf16x8 v = ((const bf16x8*)Wthg)[g];
    *(bf16x8*)(WthL + swzA(n, kb)) = v;
  }
  {
    int g = t;                            // 1024 groups-of-8 = 8192 elems
    int n = g >> 4, kb = (g & 15) * 16;
    bf16x8 v = ((const bf16x8*)Wtog)[g];
    *(bf16x8*)(WtoL + swzA(n, kb)) = v;
  }
  __syncthreads();

  #pragma unroll 1
  for (int it = 0; it < 2; ++it) {
    const int cid = blockIdx.x * 4 + it * 2 + half;
    const int b = cid >> 8, c = cid & 255;
    chunk_body<false>(x, offs, gamma, beta, bh, Al[half], WthL,
                      redW[half], redF[half], cid, cin, nullptr, nullptr);
    // og GEMM: A = [x | cell], W = WtoL; out = sigm(og)*cell (wave-local rows)
    const int arow = wave * 16 + l16;
    f32x4 acc[4];
    #pragma unroll
    for (int nt = 0; nt < 4; ++nt) acc[nt] = (f32x4){0.f, 0.f, 0.f, 0.f};
    #pragma unroll
    for (int ks = 0; ks < 4; ++ks) {
      bf16x8 av = *(const bf16x8*)(Al[half] + swzA(arow, ks * 64 + quad * 16));
      #pragma unroll
      for (int nt = 0; nt < 4; ++nt) {
        bf16x8 bf_ = *(const bf16x8*)(WtoL + swzA(nt * 16 + l16, ks * 64 + quad * 16));
        acc[nt] = __builtin_amdgcn_mfma_f32_16x16x32_bf16(av, bf_, acc[nt], 0, 0, 0);
      }
    }
    #pragma unroll
    for (int nt = 0; nt < 4; ++nt) {
      const int dcol = nt * 16 + l16;
      float bv = bo[dcol];
      #pragma unroll
      for (int r = 0; r < 4; ++r) {
        int rowl = wave * 16 + quad * 4 + r;
        int s = quad * 4 + r;
        float og = sigm(acc[nt][r] + bv);
        float cv = (float)*(const __bf16*)(Al[half] + swzA(rowl, 128 + dcol * 2));
        out[(((size_t)b * S_ + c * LCH + s) * H_ + wave) * D_ + dcol] = og * cv;
      }
    }
  }
}

extern "C" void kernel_launch(void* const* d_in, const int* in_sizes, int n_in,
                              void* d_out, int out_size, void* d_ws, size_t ws_size,
                              hipStream_t stream) {
  const float* x      = (const float*)d_in[0];
  const float* W_hid  = (const float*)d_in[1];
  const float* b_hid  = (const float*)d_in[2];
  const float* W_og   = (const float*)d_in[3];
  const float* b_og   = (const float*)d_in[4];
  const float* gamma  = (const float*)d_in[5];
  const float* beta   = (const float*)d_in[6];
  const float* initcx = (const float*)d_in[7];
  float* out = (float*)d_out;
  float* ws  = (float*)d_ws;

  // ws layout (floats):
  float*  buf0 = ws;                      // sums -> offs (in place)   524288
  float*  cA   = ws + 524288;             //                           524288
  float*  cB   = cA + 524288;             //                           524288
  float*  cin  = cB + 524288;             //                           524288
  float*  gx   = cin + 524288;            // x-offset group sums        32768
  float*  gA   = gx + 32768;              // cell group compose A       32768
  float*  gB   = gA + 32768;              // cell group compose B       32768
  __bf16* Wth  = (__bf16*)(gB + 32768);   // [192][128] bf16
  __bf16* Wto  = Wth + 24576;             // [64][128] bf16

  k_wt         <<<128,  256, 0, stream>>>(W_hid, W_og, Wth, Wto);
  k_chunk_sums <<<1024, 512, 0, stream>>>(x, buf0);
  kx_l1        <<<128,  256, 0, stream>>>(buf0, gx);
  kx_l2        <<<8,    256, 0, stream>>>(gx);
  kx_l3        <<<128,  256, 0, stream>>>(buf0, gx);
  k_gates_f    <<<256, 1024, 0, stream>>>(x, buf0, gamma, beta, Wth, b_hid, cA, cB);
  kc_l1        <<<128,  256, 0, stream>>>(cA, cB, gA, gB);
  kc_l2        <<<8,    256, 0, stream>>>(gA, gB, initcx);
  kc_l3        <<<128,  256, 0, stream>>>(cA, cB, gA, cin);
  k_og_f       <<<256, 1024, 0, stream>>>(x, buf0, gamma, beta, Wth, Wto,
                                          b_hid, b_og, cin, out);
}